// Round 2
// baseline (609.572 us; speedup 1.0000x reference)
//
#include <hip/hip_runtime.h>
#include <hip/hip_bf16.h>

using bf16 = __hip_bfloat16;
typedef float float4v __attribute__((ext_vector_type(4)));
typedef __bf16 bf16x8 __attribute__((ext_vector_type(8)));

#define B_  4
#define L_  4096
#define D_  2048
#define DI_ 256
#define M_  (B_*L_)       // 16384 rows
#define NC  64            // scan chunks per sequence
#define LC  (L_/NC)       // 64 steps per chunk

__device__ inline float bf2f(bf16 x) { return __bfloat162float(x); }
__device__ inline bf16  f2bf(float x) { return __float2bfloat16(x); }

// ---------------------------------------------------------------------------
// Dtype sniffing: gamma is ones(D). bf16 ones in memory = 0x3F80 repeated ->
// first uint32 word = 0x3F803F80. fp32 ones -> 0x3F800000. flag: 1=bf16, 0=fp32.
// ---------------------------------------------------------------------------
__global__ void detect_dtype(const unsigned* __restrict__ g, int* __restrict__ flag) {
    *flag = (g[0] == 0x3F803F80u) ? 1 : 0;
}

// Convert any-dtype input -> bf16 buffer (copy when already bf16)
__global__ void cvt_to_bf16(const void* __restrict__ in, bf16* __restrict__ out,
                            int n, const int* __restrict__ flag) {
    int i = blockIdx.x * 256 + threadIdx.x;
    if (i < n) {
        if (*flag) out[i] = ((const bf16*)in)[i];
        else       out[i] = f2bf(((const float*)in)[i]);
    }
}

// Transpose + convert: in [R,C] (flag dtype) -> out [C,R] bf16 (weights only)
__global__ void transpose_cvt(const void* __restrict__ in, bf16* __restrict__ out,
                              int R, int C, const int* __restrict__ flag) {
    int idx = blockIdx.x * 256 + threadIdx.x;
    if (idx < R * C) {
        int r = idx / C, c = idx - r * C;
        float v = *flag ? bf2f(((const bf16*)in)[idx]) : ((const float*)in)[idx];
        out[(size_t)c * R + r] = f2bf(v);
    }
}

// ---------------------------------------------------------------------------
// MFMA GEMM: C[M,N] = A[M,K] (row-major bf16) x BT[N,K] (row-major bf16)
// Block tile 128x128, BK=32, 4 waves each computing 64x64 via 4x4 of 16x16x32.
// EPI: 0 = store bf16; 1 = delta/gate (N=512, aux=z); 2 = +residual (aux=x)
// ---------------------------------------------------------------------------
#define BM 128
#define BN 128
#define BK 32
#define KP 40   // padded K-stride in LDS (bf16): 80B rows -> 2-way bank alias only (free)

template<int EPI>
__global__ __launch_bounds__(256) void gemm_bt(const bf16* __restrict__ A,
                                               const bf16* __restrict__ BT,
                                               int K, int N,
                                               bf16* __restrict__ o0,
                                               bf16* __restrict__ o1,
                                               const bf16* __restrict__ aux) {
    __shared__ bf16 As[BM * KP];
    __shared__ bf16 Bs[BN * KP];
    const int tid  = threadIdx.x;
    const int bm   = blockIdx.x, bn = blockIdx.y;
    const int lane = tid & 63, wave = tid >> 6;
    const int wm   = (wave >> 1) * 64, wn = (wave & 1) * 64;
    const int l15  = lane & 15, quad = lane >> 4;
    const int sr   = tid >> 2;          // staging row 0..63
    const int sc   = (tid & 3) * 8;     // staging k-offset {0,8,16,24}

    float4v acc[4][4] = {};

    const bf16* Ag = A  + (size_t)(bm * BM + sr) * K + sc;
    const bf16* Bg = BT + (size_t)(bn * BN + sr) * K + sc;

    for (int kk = 0; kk < K; kk += BK) {
        uint4 a0 = *(const uint4*)(Ag + kk);
        uint4 a1 = *(const uint4*)(Ag + (size_t)64 * K + kk);
        uint4 b0 = *(const uint4*)(Bg + kk);
        uint4 b1 = *(const uint4*)(Bg + (size_t)64 * K + kk);
        __syncthreads();                      // prior-iter LDS reads done
        *(uint4*)(As + sr * KP + sc)        = a0;
        *(uint4*)(As + (sr + 64) * KP + sc) = a1;
        *(uint4*)(Bs + sr * KP + sc)        = b0;
        *(uint4*)(Bs + (sr + 64) * KP + sc) = b1;
        __syncthreads();

        bf16x8 af[4], bfr[4];
#pragma unroll
        for (int i = 0; i < 4; i++) {
            af[i]  = *(const bf16x8*)(As + (wm + i * 16 + l15) * KP + quad * 8);
            bfr[i] = *(const bf16x8*)(Bs + (wn + i * 16 + l15) * KP + quad * 8);
        }
#pragma unroll
        for (int mi = 0; mi < 4; mi++)
#pragma unroll
            for (int ni = 0; ni < 4; ni++)
                acc[mi][ni] = __builtin_amdgcn_mfma_f32_16x16x32_bf16(
                    af[mi], bfr[ni], acc[mi][ni], 0, 0, 0);
    }

    // C/D layout (measured, m89): col = lane&15, row = (lane>>4)*4 + reg
#pragma unroll
    for (int mi = 0; mi < 4; mi++) {
#pragma unroll
        for (int ni = 0; ni < 4; ni++) {
#pragma unroll
            for (int r = 0; r < 4; r++) {
                int row = bm * BM + wm + mi * 16 + quad * 4 + r;
                int col = bn * BN + wn + ni * 16 + l15;
                float v = acc[mi][ni][r];
                if (EPI == 0) {
                    o0[(size_t)row * N + col] = f2bf(v);
                } else if (EPI == 1) {
                    if (col < DI_) {
                        o0[(size_t)row * DI_ + col] = f2bf(1.f / (1.f + __expf(-v)));
                    } else {
                        int d = col - DI_;
                        o1[(size_t)row * DI_ + d] =
                            f2bf(v * bf2f(aux[(size_t)row * DI_ + d]));
                    }
                } else {
                    o0[(size_t)row * N + col] =
                        f2bf(v + bf2f(aux[(size_t)row * N + col]));
                }
            }
        }
    }
}

// ---------------------------------------------------------------------------
// Chunked linear-recurrence scan: h_t = delta_t * h_{t-1} + gate_t
// ---------------------------------------------------------------------------
__global__ __launch_bounds__(256) void scan_agg(const bf16* __restrict__ delta,
                                                const bf16* __restrict__ gate,
                                                float* __restrict__ aggA,
                                                float* __restrict__ aggB, int rev) {
    int c = blockIdx.x, b = blockIdx.y, d = threadIdx.x;
    float Ap = 1.f, h = 0.f;
    for (int i = 0; i < LC; i++) {
        int t = rev ? (L_ - 1 - (c * LC + i)) : (c * LC + i);
        size_t base = ((size_t)(b * L_ + t)) * DI_ + d;
        float dlt = bf2f(delta[base]);
        float g   = bf2f(gate[base]);
        Ap *= dlt;
        h = h * dlt + g;
    }
    size_t idx = ((size_t)b * NC + c) * DI_ + d;
    aggA[idx] = Ap;
    aggB[idx] = h;
}

__global__ void scan_mid(const float* __restrict__ aggA, const float* __restrict__ aggB,
                         float* __restrict__ Hin) {
    int b = blockIdx.x, d = threadIdx.x;
    float h = 0.f;
    for (int c = 0; c < NC; c++) {
        size_t idx = ((size_t)b * NC + c) * DI_ + d;
        Hin[idx] = h;
        h = aggA[idx] * h + aggB[idx];
    }
}

__global__ __launch_bounds__(256) void scan_fix(const bf16* __restrict__ delta,
                                                const bf16* __restrict__ gate,
                                                const float* __restrict__ Hin,
                                                bf16* __restrict__ hcat,
                                                int rev, int colbase) {
    int c = blockIdx.x, b = blockIdx.y, d = threadIdx.x;
    float h = Hin[((size_t)b * NC + c) * DI_ + d];
    for (int i = 0; i < LC; i++) {
        int t = rev ? (L_ - 1 - (c * LC + i)) : (c * LC + i);
        size_t base = ((size_t)(b * L_ + t)) * DI_ + d;
        float dlt = bf2f(delta[base]);
        float g   = bf2f(gate[base]);
        h = h * dlt + g;
        hcat[((size_t)(b * L_ + t)) * (2 * DI_) + colbase + d] = f2bf(h);
    }
}

// ---------------------------------------------------------------------------
// LayerNorm over D=2048: reads bf16 ybuf, writes d_out in detected dtype
// ---------------------------------------------------------------------------
__global__ __launch_bounds__(256) void ln_kernel(const bf16* __restrict__ y,
                                                 const void* __restrict__ gamma,
                                                 const void* __restrict__ beta,
                                                 void* __restrict__ outp,
                                                 const int* __restrict__ flagp) {
    __shared__ float ss[4], ssq[4];
    const int isbf = *flagp;
    int row = blockIdx.x, tid = threadIdx.x;
    size_t base = (size_t)row * D_ + tid * 8;
    uint4 raw = *(const uint4*)(y + base);
    const unsigned short* u = (const unsigned short*)&raw;
    float v[8];
    float s = 0.f, sq = 0.f;
#pragma unroll
    for (int i = 0; i < 8; i++) {
        v[i] = __uint_as_float(((unsigned)u[i]) << 16);
        s += v[i];
        sq += v[i] * v[i];
    }
    for (int o = 32; o > 0; o >>= 1) { s += __shfl_down(s, o); sq += __shfl_down(sq, o); }
    if ((tid & 63) == 0) { ss[tid >> 6] = s; ssq[tid >> 6] = sq; }
    __syncthreads();
    float S  = ss[0] + ss[1] + ss[2] + ss[3];
    float SQ = ssq[0] + ssq[1] + ssq[2] + ssq[3];
    float mean = S * (1.f / D_);
    float var  = SQ * (1.f / D_) - mean * mean;
    float rstd = rsqrtf(var + 1e-5f);
#pragma unroll
    for (int i = 0; i < 8; i++) {
        int col = tid * 8 + i;
        float g  = isbf ? bf2f(((const bf16*)gamma)[col]) : ((const float*)gamma)[col];
        float bb = isbf ? bf2f(((const bf16*)beta)[col])  : ((const float*)beta)[col];
        float r  = (v[i] - mean) * rstd * g + bb;
        if (isbf) ((bf16*)outp)[base + i] = f2bf(r);
        else      ((float*)outp)[base + i] = r;
    }
}

// ---------------------------------------------------------------------------
extern "C" void kernel_launch(void* const* d_in, const int* in_sizes, int n_in,
                              void* d_out, int out_size, void* d_ws, size_t ws_size,
                              hipStream_t stream) {
    (void)in_sizes; (void)n_in; (void)out_size; (void)ws_size;
    const void* x     = d_in[0];
    const void* W_in  = d_in[1];
    const void* W_fwd = d_in[2];
    const void* W_bwd = d_in[3];
    const void* W_out = d_in[4];
    const void* gamma = d_in[5];
    const void* beta  = d_in[6];

    char* ws = (char*)d_ws;
    size_t off = 0;
    auto alloc = [&](size_t bytes) -> char* {
        char* p = ws + off;
        off += (bytes + 255) & ~(size_t)255;
        return p;
    };
    int*   flag   = (int*)alloc(256);
    bf16*  xbf    = (bf16*)alloc((size_t)M_ * D_ * 2);        // 67 MB
    bf16*  WinT   = (bf16*)alloc((size_t)DI_ * D_ * 2);
    bf16*  WfwdT  = (bf16*)alloc((size_t)2 * DI_ * DI_ * 2);
    bf16*  WbwdT  = (bf16*)alloc((size_t)2 * DI_ * DI_ * 2);
    bf16*  WoutT  = (bf16*)alloc((size_t)D_ * 2 * DI_ * 2);
    bf16*  z      = (bf16*)alloc((size_t)M_ * DI_ * 2);
    bf16*  del_f  = (bf16*)alloc((size_t)M_ * DI_ * 2);
    bf16*  gat_f  = (bf16*)alloc((size_t)M_ * DI_ * 2);
    bf16*  del_b  = (bf16*)alloc((size_t)M_ * DI_ * 2);
    bf16*  gat_b  = (bf16*)alloc((size_t)M_ * DI_ * 2);
    bf16*  hcat   = (bf16*)alloc((size_t)M_ * 2 * DI_ * 2);   // 16 MB
    bf16*  ybuf   = (bf16*)alloc((size_t)M_ * D_ * 2);        // 67 MB
    float* aggA_f = (float*)alloc((size_t)B_ * NC * DI_ * 4);
    float* aggB_f = (float*)alloc((size_t)B_ * NC * DI_ * 4);
    float* aggA_b = (float*)alloc((size_t)B_ * NC * DI_ * 4);
    float* aggB_b = (float*)alloc((size_t)B_ * NC * DI_ * 4);
    float* Hin_f  = (float*)alloc((size_t)B_ * NC * DI_ * 4);
    float* Hin_b  = (float*)alloc((size_t)B_ * NC * DI_ * 4);

    // 1. sniff dtype from gamma (= ones)
    detect_dtype<<<1, 1, 0, stream>>>((const unsigned*)gamma, flag);

    // 2. normalize inputs to bf16 workspace
    cvt_to_bf16<<<(M_ * D_ + 255) / 256, 256, 0, stream>>>(x, xbf, M_ * D_, flag);
    transpose_cvt<<<(D_ * DI_ + 255) / 256, 256, 0, stream>>>(W_in, WinT, D_, DI_, flag);
    transpose_cvt<<<(DI_ * 2 * DI_ + 255) / 256, 256, 0, stream>>>(W_fwd, WfwdT, DI_, 2 * DI_, flag);
    transpose_cvt<<<(DI_ * 2 * DI_ + 255) / 256, 256, 0, stream>>>(W_bwd, WbwdT, DI_, 2 * DI_, flag);
    transpose_cvt<<<(2 * DI_ * D_ + 255) / 256, 256, 0, stream>>>(W_out, WoutT, 2 * DI_, D_, flag);

    // 3. GEMM1: z = x @ W_in   [16384 x 2048] x [2048 x 256]
    gemm_bt<0><<<dim3(M_ / BM, DI_ / BN), 256, 0, stream>>>(xbf, WinT, D_, DI_, z, nullptr, nullptr);

    // 4. GEMM2 both dirs: delta = sigmoid(o[:, :256]), gate = o[:, 256:] * z
    gemm_bt<1><<<dim3(M_ / BM, 2 * DI_ / BN), 256, 0, stream>>>(z, WfwdT, DI_, 2 * DI_, del_f, gat_f, z);
    gemm_bt<1><<<dim3(M_ / BM, 2 * DI_ / BN), 256, 0, stream>>>(z, WbwdT, DI_, 2 * DI_, del_b, gat_b, z);

    // 5. chunked scans (fwd ascending, bwd descending), write concat [h_f|h_b]
    scan_agg<<<dim3(NC, B_), DI_, 0, stream>>>(del_f, gat_f, aggA_f, aggB_f, 0);
    scan_agg<<<dim3(NC, B_), DI_, 0, stream>>>(del_b, gat_b, aggA_b, aggB_b, 1);
    scan_mid<<<B_, DI_, 0, stream>>>(aggA_f, aggB_f, Hin_f);
    scan_mid<<<B_, DI_, 0, stream>>>(aggA_b, aggB_b, Hin_b);
    scan_fix<<<dim3(NC, B_), DI_, 0, stream>>>(del_f, gat_f, Hin_f, hcat, 0, 0);
    scan_fix<<<dim3(NC, B_), DI_, 0, stream>>>(del_b, gat_b, Hin_b, hcat, 1, DI_);

    // 6. GEMM3: y = hcat @ W_out + x  -> ybuf (bf16)
    gemm_bt<2><<<dim3(M_ / BM, D_ / BN), 256, 0, stream>>>(hcat, WoutT, 2 * DI_, D_, ybuf, nullptr, xbf);

    // 7. LayerNorm: ybuf -> d_out (detected dtype)
    ln_kernel<<<M_, 256, 0, stream>>>(ybuf, gamma, beta, d_out, flag);
}

// Round 3
// 571.206 us; speedup vs baseline: 1.0672x; 1.0672x over previous
//
#include <hip/hip_runtime.h>
#include <hip/hip_bf16.h>

using bf16 = __hip_bfloat16;
typedef float float4v __attribute__((ext_vector_type(4)));
typedef __bf16 bf16x8 __attribute__((ext_vector_type(8)));
typedef unsigned short ushort4v __attribute__((ext_vector_type(4)));
typedef unsigned short ushort8v __attribute__((ext_vector_type(8)));

#define B_  4
#define L_  4096
#define D_  2048
#define DI_ 256
#define M_  (B_*L_)       // 16384 rows
#define NC  64            // scan chunks per sequence
#define LC  (L_/NC)       // 64 steps per chunk

__device__ inline float bf2f(bf16 x) { return __bfloat162float(x); }
__device__ inline bf16  f2bf(float x) { return __float2bfloat16(x); }

__device__ inline void store4bf(bf16* p, float4v v) {
    ushort4v u;
#pragma unroll
    for (int i = 0; i < 4; i++) {
        bf16 h = f2bf(v[i]);
        u[i] = *(unsigned short*)&h;
    }
    *(ushort4v*)p = u;   // single 8B store
}

__device__ inline float4v load4bf(const bf16* p) {
    ushort4v u = *(const ushort4v*)p;
    float4v v;
#pragma unroll
    for (int i = 0; i < 4; i++) v[i] = __uint_as_float(((unsigned)u[i]) << 16);
    return v;
}

__device__ inline ushort8v cvt8(float4v a, float4v b) {
    ushort8v u;
#pragma unroll
    for (int i = 0; i < 4; i++) {
        bf16 h0 = f2bf(a[i]); u[i]     = *(unsigned short*)&h0;
        bf16 h1 = f2bf(b[i]); u[i + 4] = *(unsigned short*)&h1;
    }
    return u;
}

// ---------------------------------------------------------------------------
// Transpose+convert: in fp32 [R,C] -> out bf16 [C+obase, R] rows (weights only)
// ---------------------------------------------------------------------------
__global__ void transpose_cvt(const float* __restrict__ in, bf16* __restrict__ out,
                              int R, int C, int obase) {
    int idx = blockIdx.x * 256 + threadIdx.x;
    if (idx < R * C) {
        int r = idx / C, c = idx - r * C;
        out[(size_t)(c + obase) * R + r] = f2bf(in[idx]);
    }
}

// ---------------------------------------------------------------------------
// MFMA GEMM: C[M,N] = A[M,K] x BT[N,K].  A is fp32 (AF32, converted during
// staging) or bf16. 4 waves in 2x2, wave tile (TBM/2 x TBN/2), 16x16x32 MFMA.
// Operand-swapped mfma(bfr, af): lane&15 -> M index, quad*4+reg -> 4 CONSECUTIVE
// N columns => vectorized epilogue stores.
// EPI: 0 = store bf16; 1 = delta/gate 4-way split (N=1024, aux=z);
//      2 = +fp32 residual (auxf = x), store bf16
// ---------------------------------------------------------------------------
#define BK 32
#define KP 40   // padded K-stride in LDS (bf16): 80B rows -> 2-way alias only (free)

template<int TBM, int TBN, int EPI, bool AF32>
__global__ __launch_bounds__(256) void gemm_bt(const void* __restrict__ Av,
                                               const bf16* __restrict__ BT,
                                               int K, int N,
                                               bf16* __restrict__ o0, bf16* __restrict__ o1,
                                               bf16* __restrict__ o2, bf16* __restrict__ o3,
                                               const bf16* __restrict__ auxb,
                                               const float* __restrict__ auxf) {
    constexpr int MI = TBM / 32, NI = TBN / 32, AP = TBM / 64, BP = TBN / 64;
    __shared__ bf16 As[TBM * KP];
    __shared__ bf16 Bs[TBN * KP];
    const int tid  = threadIdx.x;
    const int bm   = blockIdx.x, bn = blockIdx.y;
    const int lane = tid & 63, wave = tid >> 6;
    const int wm   = (wave >> 1) * (TBM / 2), wn = (wave & 1) * (TBN / 2);
    const int l15  = lane & 15, quad = lane >> 4;
    const int sr   = tid >> 2;          // staging row 0..63
    const int sc   = (tid & 3) * 8;     // staging k-offset {0,8,16,24}

    float4v acc[MI][NI] = {};
    const float* Af = (const float*)Av;
    const bf16*  Ab = (const bf16*)Av;

    for (int kk = 0; kk < K; kk += BK) {
        float4v fa[AP][2];
        uint4   ua[AP];
        uint4   ub[BP];
        if constexpr (AF32) {
#pragma unroll
            for (int p = 0; p < AP; p++) {
                const float* src = Af + (size_t)(bm * TBM + p * 64 + sr) * K + kk + sc;
                fa[p][0] = *(const float4v*)src;
                fa[p][1] = *(const float4v*)(src + 4);
            }
        } else {
#pragma unroll
            for (int p = 0; p < AP; p++)
                ua[p] = *(const uint4*)(Ab + (size_t)(bm * TBM + p * 64 + sr) * K + kk + sc);
        }
#pragma unroll
        for (int p = 0; p < BP; p++)
            ub[p] = *(const uint4*)(BT + (size_t)(bn * TBN + p * 64 + sr) * K + kk + sc);

        __syncthreads();                      // prior-iter LDS reads done
        if constexpr (AF32) {
#pragma unroll
            for (int p = 0; p < AP; p++)
                *(ushort8v*)(As + (p * 64 + sr) * KP + sc) = cvt8(fa[p][0], fa[p][1]);
        } else {
#pragma unroll
            for (int p = 0; p < AP; p++)
                *(uint4*)(As + (p * 64 + sr) * KP + sc) = ua[p];
        }
#pragma unroll
        for (int p = 0; p < BP; p++)
            *(uint4*)(Bs + (p * 64 + sr) * KP + sc) = ub[p];
        __syncthreads();

        bf16x8 af[MI], bfr[NI];
#pragma unroll
        for (int mi = 0; mi < MI; mi++)
            af[mi] = *(const bf16x8*)(As + (wm + mi * 16 + l15) * KP + quad * 8);
#pragma unroll
        for (int ni = 0; ni < NI; ni++)
            bfr[ni] = *(const bf16x8*)(Bs + (wn + ni * 16 + l15) * KP + quad * 8);
#pragma unroll
        for (int mi = 0; mi < MI; mi++)
#pragma unroll
            for (int ni = 0; ni < NI; ni++)
                acc[mi][ni] = __builtin_amdgcn_mfma_f32_16x16x32_bf16(
                    bfr[ni], af[mi], acc[mi][ni], 0, 0, 0);
    }

    // Swapped layout: row(M) = l15-based, cols = quad*4 + reg (4 consecutive)
#pragma unroll
    for (int mi = 0; mi < MI; mi++) {
#pragma unroll
        for (int ni = 0; ni < NI; ni++) {
            int row = bm * TBM + wm + mi * 16 + l15;
            int col = bn * TBN + wn + ni * 16 + quad * 4;
            float4v v = acc[mi][ni];
            if (EPI == 0) {
                store4bf(o0 + (size_t)row * N + col, v);
            } else if (EPI == 1) {
                int sel = col >> 8, d = col & 255;
                bf16* dst = (sel == 0) ? o0 : (sel == 1) ? o1 : (sel == 2) ? o2 : o3;
                if (sel & 1) {   // gate = o * z
                    float4v z4 = load4bf(auxb + (size_t)row * DI_ + d);
#pragma unroll
                    for (int i = 0; i < 4; i++) v[i] *= z4[i];
                } else {         // delta = sigmoid(o)
#pragma unroll
                    for (int i = 0; i < 4; i++) v[i] = 1.f / (1.f + __expf(-v[i]));
                }
                store4bf(dst + (size_t)row * DI_ + d, v);
            } else {
                float4v r = *(const float4v*)(auxf + (size_t)row * N + col);
#pragma unroll
                for (int i = 0; i < 4; i++) v[i] += r[i];
                store4bf(o0 + (size_t)row * N + col, v);
            }
        }
    }
}

// ---------------------------------------------------------------------------
// Chunked linear-recurrence scan: h_t = delta_t * h_{t-1} + gate_t
// blockIdx.z = direction (0 fwd, 1 bwd/reversed)
// ---------------------------------------------------------------------------
__global__ __launch_bounds__(256) void scan_agg(const bf16* __restrict__ del_f,
                                                const bf16* __restrict__ gat_f,
                                                const bf16* __restrict__ del_b,
                                                const bf16* __restrict__ gat_b,
                                                float* __restrict__ aggA,
                                                float* __restrict__ aggB) {
    int c = blockIdx.x, b = blockIdx.y, dir = blockIdx.z, d = threadIdx.x;
    const bf16* delta = dir ? del_b : del_f;
    const bf16* gate  = dir ? gat_b : gat_f;
    float Ap = 1.f, h = 0.f;
    for (int i = 0; i < LC; i++) {
        int t = dir ? (L_ - 1 - (c * LC + i)) : (c * LC + i);
        size_t base = ((size_t)(b * L_ + t)) * DI_ + d;
        float dlt = bf2f(delta[base]);
        float g   = bf2f(gate[base]);
        Ap *= dlt;
        h = h * dlt + g;
    }
    size_t idx = (((size_t)dir * B_ + b) * NC + c) * DI_ + d;
    aggA[idx] = Ap;
    aggB[idx] = h;
}

__global__ void scan_mid(const float* __restrict__ aggA, const float* __restrict__ aggB,
                         float* __restrict__ Hin) {
    int b = blockIdx.x, dir = blockIdx.y, d = threadIdx.x;
    float h = 0.f;
    for (int c = 0; c < NC; c++) {
        size_t idx = (((size_t)dir * B_ + b) * NC + c) * DI_ + d;
        Hin[idx] = h;
        h = aggA[idx] * h + aggB[idx];
    }
}

__global__ __launch_bounds__(256) void scan_fix(const bf16* __restrict__ del_f,
                                                const bf16* __restrict__ gat_f,
                                                const bf16* __restrict__ del_b,
                                                const bf16* __restrict__ gat_b,
                                                const float* __restrict__ Hin,
                                                bf16* __restrict__ hcat) {
    int c = blockIdx.x, b = blockIdx.y, dir = blockIdx.z, d = threadIdx.x;
    const bf16* delta = dir ? del_b : del_f;
    const bf16* gate  = dir ? gat_b : gat_f;
    float h = Hin[(((size_t)dir * B_ + b) * NC + c) * DI_ + d];
    int colbase = dir * DI_;
    for (int i = 0; i < LC; i++) {
        int t = dir ? (L_ - 1 - (c * LC + i)) : (c * LC + i);
        size_t base = ((size_t)(b * L_ + t)) * DI_ + d;
        float dlt = bf2f(delta[base]);
        float g   = bf2f(gate[base]);
        h = h * dlt + g;
        hcat[((size_t)(b * L_ + t)) * (2 * DI_) + colbase + d] = f2bf(h);
    }
}

// ---------------------------------------------------------------------------
// LayerNorm over D=2048: reads bf16 ybuf, writes fp32 out. Fully vectorized.
// ---------------------------------------------------------------------------
__global__ __launch_bounds__(256) void ln_kernel(const bf16* __restrict__ y,
                                                 const float* __restrict__ gamma,
                                                 const float* __restrict__ beta,
                                                 float* __restrict__ outp) {
    __shared__ float ss[4], ssq[4];
    int row = blockIdx.x, tid = threadIdx.x;
    size_t base = (size_t)row * D_ + tid * 8;
    uint4 raw = *(const uint4*)(y + base);
    const unsigned short* u = (const unsigned short*)&raw;
    float v[8];
    float s = 0.f, sq = 0.f;
#pragma unroll
    for (int i = 0; i < 8; i++) {
        v[i] = __uint_as_float(((unsigned)u[i]) << 16);
        s += v[i];
        sq += v[i] * v[i];
    }
    for (int o = 32; o > 0; o >>= 1) { s += __shfl_down(s, o); sq += __shfl_down(sq, o); }
    if ((tid & 63) == 0) { ss[tid >> 6] = s; ssq[tid >> 6] = sq; }
    __syncthreads();
    float S  = ss[0] + ss[1] + ss[2] + ss[3];
    float SQ = ssq[0] + ssq[1] + ssq[2] + ssq[3];
    float mean = S * (1.f / D_);
    float var  = SQ * (1.f / D_) - mean * mean;
    float rstd = rsqrtf(var + 1e-5f);
    float4v g0 = *(const float4v*)(gamma + tid * 8);
    float4v g1 = *(const float4v*)(gamma + tid * 8 + 4);
    float4v b0 = *(const float4v*)(beta + tid * 8);
    float4v b1 = *(const float4v*)(beta + tid * 8 + 4);
    float4v r0, r1;
#pragma unroll
    for (int i = 0; i < 4; i++) {
        r0[i] = (v[i] - mean) * rstd * g0[i] + b0[i];
        r1[i] = (v[i + 4] - mean) * rstd * g1[i] + b1[i];
    }
    *(float4v*)(outp + base)     = r0;
    *(float4v*)(outp + base + 4) = r1;
}

// ---------------------------------------------------------------------------
extern "C" void kernel_launch(void* const* d_in, const int* in_sizes, int n_in,
                              void* d_out, int out_size, void* d_ws, size_t ws_size,
                              hipStream_t stream) {
    (void)in_sizes; (void)n_in; (void)out_size; (void)ws_size;
    const float* x     = (const float*)d_in[0];
    const float* W_in  = (const float*)d_in[1];
    const float* W_fwd = (const float*)d_in[2];
    const float* W_bwd = (const float*)d_in[3];
    const float* W_out = (const float*)d_in[4];
    const float* gamma = (const float*)d_in[5];
    const float* beta  = (const float*)d_in[6];
    float* out = (float*)d_out;

    char* ws = (char*)d_ws;
    size_t off = 0;
    auto alloc = [&](size_t bytes) -> char* {
        char* p = ws + off;
        off += (bytes + 255) & ~(size_t)255;
        return p;
    };
    bf16*  WinT   = (bf16*)alloc((size_t)DI_ * D_ * 2);           // [256, 2048]
    bf16*  WpT    = (bf16*)alloc((size_t)1024 * DI_ * 2);         // [1024, 256] fwd|bwd
    bf16*  WoutT  = (bf16*)alloc((size_t)D_ * 2 * DI_ * 2);       // [2048, 512]
    bf16*  z      = (bf16*)alloc((size_t)M_ * DI_ * 2);
    bf16*  del_f  = (bf16*)alloc((size_t)M_ * DI_ * 2);
    bf16*  gat_f  = (bf16*)alloc((size_t)M_ * DI_ * 2);
    bf16*  del_b  = (bf16*)alloc((size_t)M_ * DI_ * 2);
    bf16*  gat_b  = (bf16*)alloc((size_t)M_ * DI_ * 2);
    bf16*  hcat   = (bf16*)alloc((size_t)M_ * 2 * DI_ * 2);       // 16.8 MB
    bf16*  ybuf   = (bf16*)alloc((size_t)M_ * D_ * 2);            // 67 MB
    float* aggA   = (float*)alloc((size_t)2 * B_ * NC * DI_ * 4);
    float* aggB   = (float*)alloc((size_t)2 * B_ * NC * DI_ * 4);
    float* Hin    = (float*)alloc((size_t)2 * B_ * NC * DI_ * 4);

    // 1. weight transposes (fp32 -> bf16 [N,K])
    transpose_cvt<<<(D_ * DI_ + 255) / 256, 256, 0, stream>>>(W_in, WinT, D_, DI_, 0);
    transpose_cvt<<<(DI_ * 2 * DI_ + 255) / 256, 256, 0, stream>>>(W_fwd, WpT, DI_, 2 * DI_, 0);
    transpose_cvt<<<(DI_ * 2 * DI_ + 255) / 256, 256, 0, stream>>>(W_bwd, WpT, DI_, 2 * DI_, 2 * DI_);
    transpose_cvt<<<(2 * DI_ * D_ + 255) / 256, 256, 0, stream>>>(W_out, WoutT, 2 * DI_, D_, 0);

    // 2. GEMM1: z = x @ W_in  [16384 x 2048] x [2048 x 256], fp32 A staged->bf16
    gemm_bt<128, 64, 0, true><<<dim3(M_ / 128, DI_ / 64), 256, 0, stream>>>(
        x, WinT, D_, DI_, z, nullptr, nullptr, nullptr, nullptr, nullptr);

    // 3. GEMM2 fused dirs: o = z @ [W_fwd|W_bwd]; delta=sigmoid, gate=o*z
    gemm_bt<128, 128, 1, false><<<dim3(M_ / 128, 1024 / 128), 256, 0, stream>>>(
        z, WpT, DI_, 1024, del_f, gat_f, del_b, gat_b, z, nullptr);

    // 4. chunked scans (dir in blockIdx.z), write concat [h_f|h_b]
    scan_agg<<<dim3(NC, B_, 2), DI_, 0, stream>>>(del_f, gat_f, del_b, gat_b, aggA, aggB);
    scan_mid<<<dim3(B_, 2), DI_, 0, stream>>>(aggA, aggB, Hin);
    scan_fix<<<dim3(NC, B_, 2), DI_, 0, stream>>>(del_f, gat_f, del_b, gat_b, Hin, hcat);

    // 5. GEMM3: y = hcat @ W_out + x  [16384 x 512] x [512 x 2048] -> ybuf bf16
    gemm_bt<128, 128, 2, false><<<dim3(M_ / 128, D_ / 128), 256, 0, stream>>>(
        hcat, WoutT, 2 * DI_, D_, ybuf, nullptr, nullptr, nullptr, nullptr, x);

    // 6. LayerNorm: ybuf -> fp32 out
    ln_kernel<<<M_, 256, 0, stream>>>(ybuf, gamma, beta, out);
}